// Round 1
// baseline (49.850 us; speedup 1.0000x reference)
//
#include <hip/hip_runtime.h>
#include <hip/hip_bf16.h>

typedef __attribute__((ext_vector_type(8))) short bf16x8;
typedef __attribute__((ext_vector_type(4))) float f32x4;

#define NBH 64
#define TILE 16

__device__ __forceinline__ unsigned short f2bf(float f) {
    unsigned u = __float_as_uint(f);
    return (unsigned short)((u + 0x7fffu + ((u >> 16) & 1u)) >> 16);
}

__device__ __forceinline__ bf16x8 pack8(float4 x, float4 y) {
    bf16x8 r;
    r[0] = (short)f2bf(x.x); r[1] = (short)f2bf(x.y);
    r[2] = (short)f2bf(x.z); r[3] = (short)f2bf(x.w);
    r[4] = (short)f2bf(y.x); r[5] = (short)f2bf(y.y);
    r[6] = (short)f2bf(y.z); r[7] = (short)f2bf(y.w);
    return r;
}

// ---------------- pass 1: per-block type histogram ----------------
__global__ void k_hist(const int* __restrict__ ij, int* __restrict__ bhist, int E) {
    __shared__ int lh[10];
    if (threadIdx.x < 10) lh[threadIdx.x] = 0;
    __syncthreads();
    const int stride = gridDim.x * blockDim.x;
    for (int e = blockIdx.x * blockDim.x + threadIdx.x; e < E; e += stride)
        atomicAdd(&lh[ij[e]], 1);
    __syncthreads();
    if (threadIdx.x < 10) bhist[blockIdx.x * 10 + threadIdx.x] = lh[threadIdx.x];
}

// ---------------- pass 2: prefix sums (single block) ----------------
__global__ void k_prefix(const int* __restrict__ bhist, int* __restrict__ bbase,
                         int* __restrict__ cnt, int* __restrict__ poff) {
    __shared__ int lh[NBH * 10];
    __shared__ int lb[NBH * 10];
    __shared__ int lc[10];
    __shared__ int lp[10];
    for (int i = threadIdx.x; i < NBH * 10; i += blockDim.x) lh[i] = bhist[i];
    __syncthreads();
    if (threadIdx.x < 10) {
        const int t = threadIdx.x;
        int run = 0;
        for (int b = 0; b < NBH; ++b) { lb[b * 10 + t] = run; run += lh[b * 10 + t]; }
        lc[t] = run;
    }
    __syncthreads();
    if (threadIdx.x == 0) {
        int acc = 0;
        for (int t = 0; t < 10; ++t) { lp[t] = acc; acc += ((lc[t] + TILE - 1) / TILE) * TILE; }
    }
    __syncthreads();
    if (threadIdx.x < 10) { cnt[threadIdx.x] = lc[threadIdx.x]; poff[threadIdx.x] = lp[threadIdx.x]; }
    for (int i = threadIdx.x; i < NBH * 10; i += blockDim.x) bbase[i] = lp[i % 10] + lb[i];
}

// ---------------- pass 3: scatter edge ids into type bins ----------------
__global__ void k_scatter(const int* __restrict__ ij, const int* __restrict__ bbase,
                          int* __restrict__ perm, int E) {
    __shared__ int lbas[10];
    __shared__ int lh[10];
    if (threadIdx.x < 10) { lbas[threadIdx.x] = bbase[blockIdx.x * 10 + threadIdx.x]; lh[threadIdx.x] = 0; }
    __syncthreads();
    const int stride = gridDim.x * blockDim.x;
    for (int e = blockIdx.x * blockDim.x + threadIdx.x; e < E; e += stride) {
        const int t = ij[e];
        const int r = atomicAdd(&lh[t], 1);
        perm[lbas[t] + r] = e;
    }
}

// ---------------- pass 4: MFMA main ----------------
// grid = (NBX, 10); block = 256 (4 independent waves, each owns 16-edge tiles)
__global__ __launch_bounds__(256) void k_main(
    const int* __restrict__ perm, const int* __restrict__ cnt, const int* __restrict__ poff,
    const float* __restrict__ desc, const float* __restrict__ layer1,
    const float* __restrict__ lin_w, const float* __restrict__ lin_b,
    float* __restrict__ out) {
    const int t = blockIdx.y;
    const int cn = cnt[t];
    if (cn == 0) return;
    const int ntiles = (cn + TILE - 1) / TILE;
    const int lane = threadIdx.x & 63;
    const int w = threadIdx.x >> 6;
    const int gw = blockIdx.x * 4 + w;
    const int NW = gridDim.x * 4;
    const int col = lane & 15;            // A row / C col / B col
    const int g = lane >> 4;              // lane group 0..3
    const int kb = g * 8;                 // contiguous-8 K sub-offset
    const int pbase = poff[t];
    const float* Wt = layer1 + t * 4096;

    // resident B fragments: W_t and lin_w, bf16. B[k][n] = M[n][k] (n = output row of M)
    bf16x8 bw[4][2], bl[4][2];
    #pragma unroll
    for (int nt = 0; nt < 4; ++nt) {
        const int row = nt * 16 + col;
        #pragma unroll
        for (int kk = 0; kk < 2; ++kk) {
            const int off = row * 64 + kk * 32 + kb;
            float4 x = *(const float4*)(Wt + off);
            float4 y = *(const float4*)(Wt + off + 4);
            bw[nt][kk] = pack8(x, y);
            float4 p = *(const float4*)(lin_w + off);
            float4 q = *(const float4*)(lin_w + off + 4);
            bl[nt][kk] = pack8(p, q);
        }
    }
    float bias[4];
    #pragma unroll
    for (int nt = 0; nt < 4; ++nt) bias[nt] = lin_b[nt * 16 + col];

    for (int tile = gw; tile < ntiles; tile += NW) {
        const int jb = tile * TILE;
        const int e = perm[pbase + min(jb + col, cn - 1)];
        // A fragments: lane holds desc row (col), k = kk*32 + g*8 + [0..7]
        bf16x8 a[2];
        #pragma unroll
        for (int kk = 0; kk < 2; ++kk) {
            const float* dp = desc + (size_t)e * 64 + kk * 32 + kb;
            float4 x = *(const float4*)(dp);
            float4 y = *(const float4*)(dp + 4);
            a[kk] = pack8(x, y);
        }
        f32x4 c1[4], c2[4];
        #pragma unroll
        for (int nt = 0; nt < 4; ++nt) {
            f32x4 z = {0.f, 0.f, 0.f, 0.f};
            z = __builtin_amdgcn_mfma_f32_16x16x32_bf16(a[0], bw[nt][0], z, 0, 0, 0);
            z = __builtin_amdgcn_mfma_f32_16x16x32_bf16(a[1], bw[nt][1], z, 0, 0, 0);
            c1[nt] = z;
            f32x4 y2 = {0.f, 0.f, 0.f, 0.f};
            y2 = __builtin_amdgcn_mfma_f32_16x16x32_bf16(a[0], bl[nt][0], y2, 0, 0, 0);
            y2 = __builtin_amdgcn_mfma_f32_16x16x32_bf16(a[1], bl[nt][1], y2, 0, 0, 0);
            c2[nt] = y2;
        }
        // epilogue: C row (edge) = g*4 + r, C col (output) = nt*16 + col
        #pragma unroll
        for (int r = 0; r < 4; ++r) {
            const int m = g * 4 + r;
            const int jm = jb + m;
            if (jm < cn) {
                const int em = perm[pbase + jm];
                float* op = out + (size_t)em * 64 + col;
                #pragma unroll
                for (int nt = 0; nt < 4; ++nt) {
                    op[nt * 16] = tanhf(c1[nt][r]) + c2[nt][r] + bias[nt];
                }
            }
        }
    }
}

// ---------------- fallback (ws too small): wave-per-edge fp32 ----------------
__global__ void k_naive(const int* __restrict__ ij, const float* __restrict__ desc,
                        const float* __restrict__ layer1, const float* __restrict__ lin_w,
                        const float* __restrict__ lin_b, float* __restrict__ out, int E) {
    const int wid = (blockIdx.x * blockDim.x + threadIdx.x) >> 6;
    const int lane = threadIdx.x & 63;
    const int nw = (gridDim.x * blockDim.x) >> 6;
    for (int e = wid; e < E; e += nw) {
        const int t = ij[e];
        const float d = desc[(size_t)e * 64 + lane];
        const float* Wr = layer1 + t * 4096 + lane * 64;
        const float* Lr = lin_w + lane * 64;
        float a1 = 0.f, a2 = 0.f;
        #pragma unroll
        for (int i = 0; i < 64; i += 4) {
            float4 w4 = *(const float4*)(Wr + i);
            float4 l4 = *(const float4*)(Lr + i);
            const float d0 = __shfl(d, i), d1 = __shfl(d, i + 1);
            const float d2 = __shfl(d, i + 2), d3 = __shfl(d, i + 3);
            a1 = fmaf(w4.x, d0, fmaf(w4.y, d1, fmaf(w4.z, d2, fmaf(w4.w, d3, a1))));
            a2 = fmaf(l4.x, d0, fmaf(l4.y, d1, fmaf(l4.z, d2, fmaf(l4.w, d3, a2))));
        }
        out[(size_t)e * 64 + lane] = tanhf(a1) + a2 + lin_b[lane];
    }
}

extern "C" void kernel_launch(void* const* d_in, const int* in_sizes, int n_in,
                              void* d_out, int out_size, void* d_ws, size_t ws_size,
                              hipStream_t stream) {
    const int* ij = (const int*)d_in[0];
    const float* desc = (const float*)d_in[1];
    const float* layer1 = (const float*)d_in[2];
    const float* lin_w = (const float*)d_in[3];
    const float* lin_b = (const float*)d_in[4];
    float* out = (float*)d_out;
    const int E = in_sizes[0];

    const size_t need = (size_t)(E + 256 + NBH * 10 * 2 + 32) * sizeof(int);
    if (ws_size < need) {
        k_naive<<<2048, 256, 0, stream>>>(ij, desc, layer1, lin_w, lin_b, out, E);
        return;
    }
    int* perm = (int*)d_ws;            // E + 256 ints (padded bins)
    int* bhist = perm + E + 256;       // NBH*10
    int* bbase = bhist + NBH * 10;     // NBH*10
    int* cnt = bbase + NBH * 10;       // 10 (use 16 slots)
    int* poff = cnt + 16;              // 10

    k_hist<<<NBH, 256, 0, stream>>>(ij, bhist, E);
    k_prefix<<<1, 256, 0, stream>>>(bhist, bbase, cnt, poff);
    k_scatter<<<NBH, 256, 0, stream>>>(ij, bbase, perm, E);
    k_main<<<dim3(96, 10), 256, 0, stream>>>(perm, cnt, poff, desc, layer1, lin_w, lin_b, out);
}

// Round 2
// 31.810 us; speedup vs baseline: 1.5671x; 1.5671x over previous
//
#include <hip/hip_runtime.h>
#include <hip/hip_bf16.h>

typedef __attribute__((ext_vector_type(8))) short bf16x8;
typedef __attribute__((ext_vector_type(4))) float f32x4;

#define NBH 64
#define TILE 16
#define NBX 128

__device__ __forceinline__ unsigned short f2bf(float f) {
    unsigned u = __float_as_uint(f);
    return (unsigned short)((u + 0x7fffu + ((u >> 16) & 1u)) >> 16);
}

__device__ __forceinline__ bf16x8 pack8(float4 x, float4 y) {
    bf16x8 r;
    r[0] = (short)f2bf(x.x); r[1] = (short)f2bf(x.y);
    r[2] = (short)f2bf(x.z); r[3] = (short)f2bf(x.w);
    r[4] = (short)f2bf(y.x); r[5] = (short)f2bf(y.y);
    r[6] = (short)f2bf(y.z); r[7] = (short)f2bf(y.w);
    return r;
}

__device__ __forceinline__ float ftanh(float x) {
    float e = __expf(2.f * x);
    return 1.f - 2.f / (e + 1.f);
}

// ---------------- pass 1: per-block type histogram + weight pre-pack ----------------
// blocks [0,64): histogram; blocks [64,75): pack layer1 types 0..9 (64+t) and lin_w (74)
// packed layout per matrix: frag fi = nt*2+kk in [0,8); elem [fi][lane][j] =
//   bf16( M[nt*16 + (lane&15)][kk*32 + (lane>>4)*8 + j] )   (A-operand fragment order)
__global__ void k_hist_pack(const int* __restrict__ ij, int* __restrict__ bhist,
                            const float* __restrict__ layer1, const float* __restrict__ lin_w,
                            __hip_bfloat16* __restrict__ wpack, __hip_bfloat16* __restrict__ lpack,
                            int E) {
    if (blockIdx.x < NBH) {
        __shared__ int lh[10];
        if (threadIdx.x < 10) lh[threadIdx.x] = 0;
        __syncthreads();
        for (int e = blockIdx.x * 256 + threadIdx.x; e < E; e += NBH * 256)
            atomicAdd(&lh[ij[e]], 1);
        __syncthreads();
        if (threadIdx.x < 10) bhist[blockIdx.x * 10 + threadIdx.x] = lh[threadIdx.x];
    } else {
        const int t = blockIdx.x - NBH;
        const float* src = (t < 10) ? (layer1 + t * 4096) : lin_w;
        __hip_bfloat16* dst = (t < 10) ? (wpack + t * 4096) : lpack;
        for (int idx = threadIdx.x; idx < 512; idx += 256) {
            const int fi = idx >> 6, l = idx & 63;
            const int nt = fi >> 1, kk = fi & 1;
            const float* sp = src + (nt * 16 + (l & 15)) * 64 + kk * 32 + (l >> 4) * 8;
            float4 x = *(const float4*)sp;
            float4 y = *(const float4*)(sp + 4);
            *(bf16x8*)(dst + fi * 512 + l * 8) = pack8(x, y);
        }
    }
}

// ---------------- pass 2: fused prefix + scatter ----------------
// Every block redundantly scans the 64x10 histogram (tiny) to get its own bases.
__global__ void k_scatter2(const int* __restrict__ ij, const int* __restrict__ bhist,
                           int* __restrict__ perm, int* __restrict__ cnt, int* __restrict__ poff,
                           int E) {
    __shared__ int lh[NBH * 10];
    __shared__ int lbas[10];
    __shared__ int lcnt[10];
    __shared__ int lpof[10];
    for (int i = threadIdx.x; i < NBH * 10; i += 256) lh[i] = bhist[i];
    __syncthreads();
    if (threadIdx.x < 10) {
        const int t = threadIdx.x;
        int pre = 0, tot = 0;
        for (int b = 0; b < NBH; ++b) {
            if (b == (int)blockIdx.x) pre = tot;
            tot += lh[b * 10 + t];
        }
        lcnt[t] = tot;
        lbas[t] = pre;
    }
    __syncthreads();
    if (threadIdx.x == 0) {
        int acc = 0;
        for (int t = 0; t < 10; ++t) { lpof[t] = acc; acc += ((lcnt[t] + TILE - 1) / TILE) * TILE; }
    }
    __syncthreads();
    if (threadIdx.x < 10) {
        lbas[threadIdx.x] += lpof[threadIdx.x];
        if (blockIdx.x == 0) { cnt[threadIdx.x] = lcnt[threadIdx.x]; poff[threadIdx.x] = lpof[threadIdx.x]; }
        lh[threadIdx.x] = 0;  // reuse as rank counters (all reads of lh are done)
    }
    __syncthreads();
    for (int e = blockIdx.x * 256 + threadIdx.x; e < E; e += NBH * 256) {
        const int t = ij[e];
        const int r = atomicAdd(&lh[t], 1);
        perm[lbas[t] + r] = e;
    }
}

// ---------------- pass 3: MFMA main ----------------
// A = weights (M = 64 outputs, 4 nt-blocks), B = desc (N = 16 edges), K = 64.
// D layout: col(lane&15) = edge, row((lane>>4)*4+r) = output within nt-block.
// Per lane per nt: 4 consecutive outputs -> one float4 store.
__global__ __launch_bounds__(256) void k_main(
    const int* __restrict__ perm, const int* __restrict__ cnt, const int* __restrict__ poff,
    const float* __restrict__ desc, const __hip_bfloat16* __restrict__ wpack,
    const __hip_bfloat16* __restrict__ lpack, const float* __restrict__ lin_b,
    float* __restrict__ out) {
    const int t = blockIdx.y;
    const int cn = cnt[t];
    if (cn == 0) return;
    const int ntiles = (cn + TILE - 1) / TILE;
    const int lane = threadIdx.x & 63;
    const int w = threadIdx.x >> 6;
    const int gw = blockIdx.x * 4 + w;
    const int col = lane & 15;
    const int g = lane >> 4;
    const int kb = g * 8;
    const int pbase = poff[t];
    const __hip_bfloat16* wp = wpack + t * 4096;

    bf16x8 aw[4][2], al[4][2];
    #pragma unroll
    for (int fi = 0; fi < 8; ++fi) {
        aw[fi >> 1][fi & 1] = *(const bf16x8*)(wp + fi * 512 + lane * 8);
        al[fi >> 1][fi & 1] = *(const bf16x8*)(lpack + fi * 512 + lane * 8);
    }
    float4 bias[4];
    #pragma unroll
    for (int nt = 0; nt < 4; ++nt) bias[nt] = *(const float4*)(lin_b + nt * 16 + g * 4);

    for (int tile = gw; tile < ntiles; tile += NBX * 4) {
        const int jb = tile * TILE;
        const int e = perm[pbase + min(jb + col, cn - 1)];
        bf16x8 b[2];
        #pragma unroll
        for (int kk = 0; kk < 2; ++kk) {
            const float* dp = desc + (size_t)e * 64 + kk * 32 + kb;
            float4 x = *(const float4*)dp;
            float4 y = *(const float4*)(dp + 4);
            b[kk] = pack8(x, y);
        }
        #pragma unroll
        for (int nt = 0; nt < 4; ++nt) {
            f32x4 z = {0.f, 0.f, 0.f, 0.f}, y2 = {0.f, 0.f, 0.f, 0.f};
            z = __builtin_amdgcn_mfma_f32_16x16x32_bf16(aw[nt][0], b[0], z, 0, 0, 0);
            z = __builtin_amdgcn_mfma_f32_16x16x32_bf16(aw[nt][1], b[1], z, 0, 0, 0);
            y2 = __builtin_amdgcn_mfma_f32_16x16x32_bf16(al[nt][0], b[0], y2, 0, 0, 0);
            y2 = __builtin_amdgcn_mfma_f32_16x16x32_bf16(al[nt][1], b[1], y2, 0, 0, 0);
            float4 r;
            r.x = ftanh(z[0]) + y2[0] + bias[nt].x;
            r.y = ftanh(z[1]) + y2[1] + bias[nt].y;
            r.z = ftanh(z[2]) + y2[2] + bias[nt].z;
            r.w = ftanh(z[3]) + y2[3] + bias[nt].w;
            *(float4*)(out + (size_t)e * 64 + nt * 16 + g * 4) = r;
        }
    }
}

// ---------------- fallback (ws too small): wave-per-edge fp32 ----------------
__global__ void k_naive(const int* __restrict__ ij, const float* __restrict__ desc,
                        const float* __restrict__ layer1, const float* __restrict__ lin_w,
                        const float* __restrict__ lin_b, float* __restrict__ out, int E) {
    const int wid = (blockIdx.x * blockDim.x + threadIdx.x) >> 6;
    const int lane = threadIdx.x & 63;
    const int nw = (gridDim.x * blockDim.x) >> 6;
    for (int e = wid; e < E; e += nw) {
        const int t = ij[e];
        const float d = desc[(size_t)e * 64 + lane];
        const float* Wr = layer1 + t * 4096 + lane * 64;
        const float* Lr = lin_w + lane * 64;
        float a1 = 0.f, a2 = 0.f;
        #pragma unroll
        for (int i = 0; i < 64; i += 4) {
            float4 w4 = *(const float4*)(Wr + i);
            float4 l4 = *(const float4*)(Lr + i);
            const float d0 = __shfl(d, i), d1 = __shfl(d, i + 1);
            const float d2 = __shfl(d, i + 2), d3 = __shfl(d, i + 3);
            a1 = fmaf(w4.x, d0, fmaf(w4.y, d1, fmaf(w4.z, d2, fmaf(w4.w, d3, a1))));
            a2 = fmaf(l4.x, d0, fmaf(l4.y, d1, fmaf(l4.z, d2, fmaf(l4.w, d3, a2))));
        }
        out[(size_t)e * 64 + lane] = tanhf(a1) + a2 + lin_b[lane];
    }
}

extern "C" void kernel_launch(void* const* d_in, const int* in_sizes, int n_in,
                              void* d_out, int out_size, void* d_ws, size_t ws_size,
                              hipStream_t stream) {
    const int* ij = (const int*)d_in[0];
    const float* desc = (const float*)d_in[1];
    const float* layer1 = (const float*)d_in[2];
    const float* lin_w = (const float*)d_in[3];
    const float* lin_b = (const float*)d_in[4];
    float* out = (float*)d_out;
    const int E = in_sizes[0];

    const size_t need = (size_t)(E + 256 + NBH * 10 + 32) * sizeof(int)
                      + (size_t)11 * 4096 * sizeof(__hip_bfloat16) + 64;
    if (ws_size < need) {
        k_naive<<<2048, 256, 0, stream>>>(ij, desc, layer1, lin_w, lin_b, out, E);
        return;
    }
    int* perm = (int*)d_ws;                    // E + 256 ints (padded bins)
    int* bhist = perm + E + 256;               // NBH*10 = 640
    int* cnt = bhist + NBH * 10;               // 16 slots
    int* poff = cnt + 16;                      // 16 slots
    __hip_bfloat16* wpack = (__hip_bfloat16*)(poff + 16);  // 10*4096 bf16 (16B-aligned)
    __hip_bfloat16* lpack = wpack + 10 * 4096;             // 4096 bf16

    k_hist_pack<<<NBH + 11, 256, 0, stream>>>(ij, bhist, layer1, lin_w, wpack, lpack, E);
    k_scatter2<<<NBH, 256, 0, stream>>>(ij, bhist, perm, cnt, poff, E);
    k_main<<<dim3(NBX, 10), 256, 0, stream>>>(perm, cnt, poff, desc, wpack, lpack, lin_b, out);
}